// Round 3
// baseline (184.893 us; speedup 1.0000x reference)
//
#include <hip/hip_runtime.h>
#include <hip/hip_bf16.h>

#define B_ 2
#define R_ 1
#define A_ 16
#define S_ 14
#define F_ 1024
#define N_ 512
#define D_ (S_*N_)        // 7168
#define M_ (B_*R_*A_)     // 32
#define KK_ (2*D_)        // 14336
#define BE 64
#define ETILES (D_/BE)    // 112

typedef __attribute__((ext_vector_type(8))) short bf16x8;
typedef __attribute__((ext_vector_type(4))) float f32x4;

static __device__ inline short f2bf(float f) {
    __hip_bfloat16 h = __float2bfloat16(f);
    return *reinterpret_cast<short*>(&h);
}
static __device__ inline float bf2f(short s) {
    unsigned int u = ((unsigned int)(unsigned short)s) << 16;
    return __uint_as_float(u);
}

// Build packed A' [64][14336] bf16: rows 0..31: [yr|yi], rows 32..63: [yi|-yr]
__global__ void prep_kernel(const float* __restrict__ xr, const float* __restrict__ xi,
                            const int* __restrict__ sc, short* __restrict__ Ap) {
    int idx = blockIdx.x * blockDim.x + threadIdx.x;
    if (idx >= 64 * KK_) return;
    int k = idx % KK_;
    int r = idx / KK_;
    int m = r & 31;
    int half = (k >= D_) ? 1 : 0;
    int d = half ? (k - D_) : k;
    int s = d >> 9;
    int n = d & 511;
    int f = sc[n];
    const float* base = (r < 32) ? (half ? xi : xr) : (half ? xr : xi);
    float v = base[(m * S_ + s) * F_ + f];
    if (r >= 32 && half) v = -v;
    Ap[idx] = f2bf(v);
}

__global__ void zero_kernel(float4* __restrict__ out, int n4) {
    int i = blockIdx.x * blockDim.x + threadIdx.x;
    if (i < n4) out[i] = make_float4(0.f, 0.f, 0.f, 0.f);
}

// Barrier-free register-pipelined GEMM. Each wave owns 16 output cols (e),
// all 64 packed-A rows. B rows stream from HBM straight to VGPRs (depth-2
// ping-pong); A' is L2-resident. No LDS, no __syncthreads.
template<int KSPLIT, int PARTIALS>
__global__ __launch_bounds__(256) void gemm_kernel(
    const short* __restrict__ Ap,
    const float* __restrict__ Cre, const float* __restrict__ Cim,
    const int* __restrict__ sc,
    void* __restrict__ outp)
{
    constexpr int KBLK = KK_ / KSPLIT;   // 512 for KSPLIT=28
    const int etile = blockIdx.x;        // 0..111
    const int ks    = blockIdx.y;        // 0..KSPLIT-1
    const int tid   = threadIdx.x;
    const int wave  = tid >> 6;
    const int lane  = tid & 63;
    const int l16   = lane & 15;
    const int kg    = lane >> 4;

    const int e_lane = etile * BE + wave * 16 + l16;     // output col = C row
    const float* Cp  = (ks < KSPLIT / 2) ? Cre : Cim;
    const int kc = (ks % (KSPLIT / 2)) * KBLK;           // col base within C half
    const int ka = ks * KBLK;                            // k base in packed A'

    const float* crow = Cp + (size_t)e_lane * D_ + kc + kg * 8;
    const short* ab   = Ap + (size_t)l16 * KK_ + ka + kg * 8;

#define LB(b0, b1, off) do { \
        b0 = *reinterpret_cast<const f32x4*>(crow + (off)); \
        b1 = *reinterpret_cast<const f32x4*>(crow + (off) + 4); } while (0)
#define LA(a0, a1, a2, a3, off) do { \
        a0 = *reinterpret_cast<const bf16x8*>(ab + (off)); \
        a1 = *reinterpret_cast<const bf16x8*>(ab + (size_t)16 * KK_ + (off)); \
        a2 = *reinterpret_cast<const bf16x8*>(ab + (size_t)32 * KK_ + (off)); \
        a3 = *reinterpret_cast<const bf16x8*>(ab + (size_t)48 * KK_ + (off)); } while (0)
#define CMP(b0, b1, a0, a1, a2, a3) do { \
        bf16x8 bf; \
        bf[0] = f2bf(b0.x); bf[1] = f2bf(b0.y); bf[2] = f2bf(b0.z); bf[3] = f2bf(b0.w); \
        bf[4] = f2bf(b1.x); bf[5] = f2bf(b1.y); bf[6] = f2bf(b1.z); bf[7] = f2bf(b1.w); \
        acc0 = __builtin_amdgcn_mfma_f32_16x16x32_bf16(a0, bf, acc0, 0, 0, 0); \
        acc1 = __builtin_amdgcn_mfma_f32_16x16x32_bf16(a1, bf, acc1, 0, 0, 0); \
        acc2 = __builtin_amdgcn_mfma_f32_16x16x32_bf16(a2, bf, acc2, 0, 0, 0); \
        acc3 = __builtin_amdgcn_mfma_f32_16x16x32_bf16(a3, bf, acc3, 0, 0, 0); } while (0)

    f32x4 acc0 = {0.f,0.f,0.f,0.f}, acc1 = {0.f,0.f,0.f,0.f};
    f32x4 acc2 = {0.f,0.f,0.f,0.f}, acc3 = {0.f,0.f,0.f,0.f};

    f32x4 pb0, pb1, qb0, qb1;
    bf16x8 pa0, pa1, pa2, pa3, qa0, qa1, qa2, qa3;

    LB(pb0, pb1, 0);
    LA(pa0, pa1, pa2, pa3, 0);

    int kk = 0;
    for (; kk < KBLK - 64; kk += 64) {
        LB(qb0, qb1, kk + 32);
        LA(qa0, qa1, qa2, qa3, kk + 32);
        CMP(pb0, pb1, pa0, pa1, pa2, pa3);
        LB(pb0, pb1, kk + 64);
        LA(pa0, pa1, pa2, pa3, kk + 64);
        CMP(qb0, qb1, qa0, qa1, qa2, qa3);
    }
    // tail pair (kk == KBLK-64): no further prefetch
    LB(qb0, qb1, kk + 32);
    LA(qa0, qa1, qa2, qa3, kk + 32);
    CMP(pb0, pb1, pa0, pa1, pa2, pa3);
    CMP(qb0, qb1, qa0, qa1, qa2, qa3);

#undef LB
#undef LA
#undef CMP

    if (PARTIALS) {
        short* part = (short*)outp + (size_t)ks * (64 * D_);
        #pragma unroll
        for (int mt = 0; mt < 4; ++mt) {
            f32x4 a = (mt == 0) ? acc0 : (mt == 1) ? acc1 : (mt == 2) ? acc2 : acc3;
            int rbase = mt * 16 + kg * 4;    // D-frag: row=(lane>>4)*4+reg, col=lane&15
            #pragma unroll
            for (int r = 0; r < 4; ++r)
                part[(size_t)(rbase + r) * D_ + e_lane] = f2bf(a[r]);
        }
    } else {
        float* out = (float*)outp;
        int s = e_lane >> 9, n = e_lane & 511;
        int f = sc[n];
        #pragma unroll
        for (int mt = 0; mt < 4; ++mt) {
            f32x4 a = (mt == 0) ? acc0 : (mt == 1) ? acc1 : (mt == 2) ? acc2 : acc3;
            int rbase = mt * 16 + kg * 4;
            #pragma unroll
            for (int r = 0; r < 4; ++r) {
                int rr = rbase + r;
                int pp = rr >> 5, m = rr & 31;
                atomicAdd(&out[((pp * M_ + m) * S_ + s) * F_ + f], a[r]);
            }
        }
    }
}

// Sum KSPLIT bf16 partials (8 e-elements per thread), scatter into [2,B,R,A,S,F]
template<int KSPLIT>
__global__ void reduce_kernel(const short* __restrict__ part, const int* __restrict__ sc,
                              float* __restrict__ out) {
    int t = blockIdx.x * blockDim.x + threadIdx.x;
    if (t >= 64 * D_ / 8) return;
    int base = t * 8;
    int e0 = base % D_;
    int r  = base / D_;
    float v[8] = {0.f,0.f,0.f,0.f,0.f,0.f,0.f,0.f};
    #pragma unroll
    for (int ksp = 0; ksp < KSPLIT; ++ksp) {
        bf16x8 x = *reinterpret_cast<const bf16x8*>(&part[(size_t)ksp * (64 * D_) + base]);
        #pragma unroll
        for (int j = 0; j < 8; ++j) v[j] += bf2f(x[j]);
    }
    int pp = r >> 5, m = r & 31, s = e0 >> 9, n0 = e0 & 511;
    float* ob = &out[((pp * M_ + m) * S_ + s) * F_];
    #pragma unroll
    for (int j = 0; j < 8; ++j) ob[sc[n0 + j]] = v[j];
}

extern "C" void kernel_launch(void* const* d_in, const int* in_sizes, int n_in,
                              void* d_out, int out_size, void* d_ws, size_t ws_size,
                              hipStream_t stream) {
    const float* xr  = (const float*)d_in[0];
    const float* xi  = (const float*)d_in[1];
    const float* Cre = (const float*)d_in[2];
    const float* Cim = (const float*)d_in[3];
    const int*   sc  = (const int*)d_in[4];
    float* out = (float*)d_out;

    short* Ap = (short*)d_ws;
    const size_t partOff = 2u * 1024u * 1024u;
    const size_t need28  = partOff + 28ull * 64 * D_ * 2;
    const size_t need16  = partOff + 16ull * 64 * D_ * 2;

    prep_kernel<<<dim3((64 * KK_ + 255) / 256), 256, 0, stream>>>(xr, xi, sc, Ap);
    zero_kernel<<<dim3((917504 / 4 + 255) / 256), 256, 0, stream>>>((float4*)out, 917504 / 4);

    const int rthreads = 64 * D_ / 8;
    if (ws_size >= need28) {
        short* part = (short*)((char*)d_ws + partOff);
        gemm_kernel<28, 1><<<dim3(ETILES, 28), 256, 0, stream>>>(Ap, Cre, Cim, sc, part);
        reduce_kernel<28><<<dim3((rthreads + 255) / 256), 256, 0, stream>>>(part, sc, out);
    } else if (ws_size >= need16) {
        short* part = (short*)((char*)d_ws + partOff);
        gemm_kernel<16, 1><<<dim3(ETILES, 16), 256, 0, stream>>>(Ap, Cre, Cim, sc, part);
        reduce_kernel<16><<<dim3((rthreads + 255) / 256), 256, 0, stream>>>(part, sc, out);
    } else {
        gemm_kernel<16, 0><<<dim3(ETILES, 16), 256, 0, stream>>>(Ap, Cre, Cim, sc, out);
    }
}

// Round 4
// 107.681 us; speedup vs baseline: 1.7170x; 1.7170x over previous
//
#include <hip/hip_runtime.h>
#include <hip/hip_bf16.h>

#define B_ 2
#define R_ 1
#define A_ 16
#define S_ 14
#define F_ 1024
#define N_ 512
#define D_ (S_*N_)        // 7168
#define M_ (B_*R_*A_)     // 32
#define KK_ (2*D_)        // 14336
#define BE 64
#define ETILES (D_/BE)    // 112

typedef __attribute__((ext_vector_type(8))) short bf16x8;
typedef __attribute__((ext_vector_type(4))) float f32x4;

static __device__ inline short f2bf(float f) {
    __hip_bfloat16 h = __float2bfloat16(f);
    return *reinterpret_cast<short*>(&h);
}
static __device__ inline float bf2f(short s) {
    unsigned int u = ((unsigned int)(unsigned short)s) << 16;
    return __uint_as_float(u);
}

#define LDSP(p) ((__attribute__((address_space(3))) void*)(p))
#define GLBP(p) ((const __attribute__((address_space(1))) void*)(p))

// Build packed A' in 16B-unit-transposed layout: Ap[g][r][j] for global k = g*8+j,
// row r: rows 0..31: [yr|yi], rows 32..63: [yi|-yr]  (k<D: first half)
__global__ void prep_kernel(const float* __restrict__ xr, const float* __restrict__ xi,
                            const int* __restrict__ sc, short* __restrict__ Ap) {
    int idx = blockIdx.x * blockDim.x + threadIdx.x;
    if (idx >= 64 * KK_) return;
    int k = idx % KK_;
    int r = idx / KK_;
    int m = r & 31;
    int half = (k >= D_) ? 1 : 0;
    int d = half ? (k - D_) : k;
    int s = d >> 9;
    int n = d & 511;
    int f = sc[n];
    const float* base = (r < 32) ? (half ? xi : xr) : (half ? xr : xi);
    float v = base[(m * S_ + s) * F_ + f];
    if (r >= 32 && half) v = -v;
    Ap[((size_t)(k >> 3) * 64 + r) * 8 + (k & 7)] = f2bf(v);
}

__global__ void zero_kernel(float4* __restrict__ out, int n4) {
    int i = blockIdx.x * blockDim.x + threadIdx.x;
    if (i < n4) out[i] = make_float4(0.f, 0.f, 0.f, 0.f);
}

// LDS-staged GEMM, 3-buffer, distance-2 prefetch, counted vmcnt + raw barriers.
template<int KSPLIT, int PARTIALS>
__global__ __launch_bounds__(256) void gemm_kernel(
    const short* __restrict__ Ap,
    const float* __restrict__ Cre, const float* __restrict__ Cim,
    const int* __restrict__ sc,
    void* __restrict__ outp)
{
    constexpr int KBLK = KK_ / KSPLIT;   // k per block (one C half)
    constexpr int NCH  = KBLK / 32;      // 32-k chunks
    __shared__ float Bl[3][64 * 32];     // 8 KB/buf, XOR-swizzled C tile (f32)
    __shared__ short Al[3][64 * 32];     // 4 KB/buf, [g_local][row][8] A' tile

    const int etile = blockIdx.x;
    const int ks    = blockIdx.y;
    const int tid   = threadIdx.x;
    const int wave  = tid >> 6;
    const int lane  = tid & 63;
    const int l16   = lane & 15;
    const int kg    = lane >> 4;

    const float* Cp = (ks < KSPLIT / 2) ? Cre : Cim;
    const int kc = (ks % (KSPLIT / 2)) * KBLK;   // col base within C half
    const int ka = ks * KBLK;                    // k base in packed A'

    // B staging sources: thread stages 2x16B. Unit U = q*256+tid ->
    // row = U>>3, stored unit u' = U&7, source unit u = u' ^ (row&7).
    const float* bsrc[2];
    #pragma unroll
    for (int q = 0; q < 2; ++q) {
        int U = q * 256 + tid;
        int row = U >> 3;
        int u = (U & 7) ^ (row & 7);
        bsrc[q] = Cp + (size_t)(etile * BE + row) * D_ + kc + u * 4;
    }
    // A staging source: transposed layout -> chunk c is 4 KB contiguous.
    const short* asrc = Ap + ((size_t)(ka >> 3) * 64) * 8 + tid * 8;

#define STAGE(c) do { \
        int bf_ = (c) % 3; \
        __builtin_amdgcn_global_load_lds(GLBP(bsrc[0] + (size_t)(c) * 32), \
                                         LDSP(&Bl[bf_][(0 * 256 + tid) * 4]), 16, 0, 0); \
        __builtin_amdgcn_global_load_lds(GLBP(bsrc[1] + (size_t)(c) * 32), \
                                         LDSP(&Bl[bf_][(1 * 256 + tid) * 4]), 16, 0, 0); \
        __builtin_amdgcn_global_load_lds(GLBP(asrc + (size_t)(c) * 2048), \
                                         LDSP(&Al[bf_][tid * 8]), 16, 0, 0); \
    } while (0)

    STAGE(0);
    STAGE(1);

    f32x4 acc0 = {0.f,0.f,0.f,0.f}, acc1 = {0.f,0.f,0.f,0.f};
    f32x4 acc2 = {0.f,0.f,0.f,0.f}, acc3 = {0.f,0.f,0.f,0.f};

    const int row  = wave * 16 + l16;       // e within block tile
    const int swz  = row & 7;
    const int boff = row * 32;
    const int u0 = ((kg * 2 + 0) ^ swz) * 4;
    const int u1 = ((kg * 2 + 1) ^ swz) * 4;

    for (int c = 0; c < NCH; ++c) {
        if (c < NCH - 1) asm volatile("s_waitcnt vmcnt(3)" ::: "memory");
        else             asm volatile("s_waitcnt vmcnt(0)" ::: "memory");
        __builtin_amdgcn_sched_barrier(0);
        __builtin_amdgcn_s_barrier();      // all waves: chunk c is in LDS

        const int buf = c % 3;
        f32x4 b0 = *reinterpret_cast<const f32x4*>(&Bl[buf][boff + u0]);
        f32x4 b1 = *reinterpret_cast<const f32x4*>(&Bl[buf][boff + u1]);
        bf16x8 a0 = *reinterpret_cast<const bf16x8*>(&Al[buf][(kg * 64 + 0 * 16 + l16) * 8]);
        bf16x8 a1 = *reinterpret_cast<const bf16x8*>(&Al[buf][(kg * 64 + 1 * 16 + l16) * 8]);
        bf16x8 a2 = *reinterpret_cast<const bf16x8*>(&Al[buf][(kg * 64 + 2 * 16 + l16) * 8]);
        bf16x8 a3 = *reinterpret_cast<const bf16x8*>(&Al[buf][(kg * 64 + 3 * 16 + l16) * 8]);
        asm volatile("s_waitcnt lgkmcnt(0)" ::: "memory");
        __builtin_amdgcn_sched_barrier(0);
        __builtin_amdgcn_s_barrier();      // all waves done reading buf[(c)%3]

        if (c + 2 < NCH) STAGE(c + 2);     // overwrites buf[(c+2)%3] (=(c-1)%3)

        bf16x8 bfv;
        bfv[0] = f2bf(b0.x); bfv[1] = f2bf(b0.y); bfv[2] = f2bf(b0.z); bfv[3] = f2bf(b0.w);
        bfv[4] = f2bf(b1.x); bfv[5] = f2bf(b1.y); bfv[6] = f2bf(b1.z); bfv[7] = f2bf(b1.w);
        acc0 = __builtin_amdgcn_mfma_f32_16x16x32_bf16(a0, bfv, acc0, 0, 0, 0);
        acc1 = __builtin_amdgcn_mfma_f32_16x16x32_bf16(a1, bfv, acc1, 0, 0, 0);
        acc2 = __builtin_amdgcn_mfma_f32_16x16x32_bf16(a2, bfv, acc2, 0, 0, 0);
        acc3 = __builtin_amdgcn_mfma_f32_16x16x32_bf16(a3, bfv, acc3, 0, 0, 0);
    }
#undef STAGE

    const int e_lane = etile * BE + row;
    if (PARTIALS) {
        short* part = (short*)outp + (size_t)ks * (64 * D_);
        #pragma unroll
        for (int mt = 0; mt < 4; ++mt) {
            f32x4 a = (mt == 0) ? acc0 : (mt == 1) ? acc1 : (mt == 2) ? acc2 : acc3;
            int rbase = mt * 16 + kg * 4;    // D-frag: row=(lane>>4)*4+reg, col=lane&15
            #pragma unroll
            for (int r = 0; r < 4; ++r)
                part[(size_t)(rbase + r) * D_ + e_lane] = f2bf(a[r]);
        }
    } else {
        float* out = (float*)outp;
        int s = e_lane >> 9, n = e_lane & 511;
        int f = sc[n];
        #pragma unroll
        for (int mt = 0; mt < 4; ++mt) {
            f32x4 a = (mt == 0) ? acc0 : (mt == 1) ? acc1 : (mt == 2) ? acc2 : acc3;
            int rbase = mt * 16 + kg * 4;
            #pragma unroll
            for (int r = 0; r < 4; ++r) {
                int rr = rbase + r;
                int pp = rr >> 5, m = rr & 31;
                atomicAdd(&out[((pp * M_ + m) * S_ + s) * F_ + f], a[r]);
            }
        }
    }
}

// Sum KSPLIT bf16 partials (8 e-elements per thread), scatter into [2,B,R,A,S,F]
template<int KSPLIT>
__global__ void reduce_kernel(const short* __restrict__ part, const int* __restrict__ sc,
                              float* __restrict__ out) {
    int t = blockIdx.x * blockDim.x + threadIdx.x;
    if (t >= 64 * D_ / 8) return;
    int base = t * 8;
    int e0 = base % D_;
    int r  = base / D_;
    float v[8] = {0.f,0.f,0.f,0.f,0.f,0.f,0.f,0.f};
    #pragma unroll
    for (int ksp = 0; ksp < KSPLIT; ++ksp) {
        bf16x8 x = *reinterpret_cast<const bf16x8*>(&part[(size_t)ksp * (64 * D_) + base]);
        #pragma unroll
        for (int j = 0; j < 8; ++j) v[j] += bf2f(x[j]);
    }
    int pp = r >> 5, m = r & 31, s = e0 >> 9, n0 = e0 & 511;
    float* ob = &out[((pp * M_ + m) * S_ + s) * F_];
    #pragma unroll
    for (int j = 0; j < 8; ++j) ob[sc[n0 + j]] = v[j];
}

extern "C" void kernel_launch(void* const* d_in, const int* in_sizes, int n_in,
                              void* d_out, int out_size, void* d_ws, size_t ws_size,
                              hipStream_t stream) {
    const float* xr  = (const float*)d_in[0];
    const float* xi  = (const float*)d_in[1];
    const float* Cre = (const float*)d_in[2];
    const float* Cim = (const float*)d_in[3];
    const int*   sc  = (const int*)d_in[4];
    float* out = (float*)d_out;

    short* Ap = (short*)d_ws;
    const size_t partOff = 2u * 1024u * 1024u;
    const size_t need28  = partOff + 28ull * 64 * D_ * 2;
    const size_t need16  = partOff + 16ull * 64 * D_ * 2;

    prep_kernel<<<dim3((64 * KK_ + 255) / 256), 256, 0, stream>>>(xr, xi, sc, Ap);
    zero_kernel<<<dim3((917504 / 4 + 255) / 256), 256, 0, stream>>>((float4*)out, 917504 / 4);

    const int rthreads = 64 * D_ / 8;
    if (ws_size >= need28) {
        short* part = (short*)((char*)d_ws + partOff);
        gemm_kernel<28, 1><<<dim3(ETILES, 28), 256, 0, stream>>>(Ap, Cre, Cim, sc, part);
        reduce_kernel<28><<<dim3((rthreads + 255) / 256), 256, 0, stream>>>(part, sc, out);
    } else if (ws_size >= need16) {
        short* part = (short*)((char*)d_ws + partOff);
        gemm_kernel<16, 1><<<dim3(ETILES, 16), 256, 0, stream>>>(Ap, Cre, Cim, sc, part);
        reduce_kernel<16><<<dim3((rthreads + 255) / 256), 256, 0, stream>>>(part, sc, out);
    } else {
        gemm_kernel<16, 0><<<dim3(ETILES, 16), 256, 0, stream>>>(Ap, Cre, Cim, sc, out);
    }
}